// Round 8
// baseline (249.960 us; speedup 1.0000x reference)
//
#include <hip/hip_runtime.h>
#include <hip/hip_bf16.h>
#include <stdint.h>

typedef _Float16 f16;
typedef _Float16 f16x8 __attribute__((ext_vector_type(8)));
typedef _Float16 f16x4 __attribute__((ext_vector_type(4)));
typedef float    f32x4 __attribute__((ext_vector_type(4)));

#define BB 4
#define CC 512
#define TT 2048

__device__ __forceinline__ void gload16(const void* g, void* l) {
  __builtin_amdgcn_global_load_lds((const __attribute__((address_space(1))) void*)g,
                                   (__attribute__((address_space(3))) void*)l, 16, 0, 0);
}

template <int N>
__device__ __forceinline__ void s_wait_vmcnt() {
  if constexpr (N == 0)      asm volatile("s_waitcnt vmcnt(0)" ::: "memory");
  else if constexpr (N == 4) asm volatile("s_waitcnt vmcnt(4)" ::: "memory");
  else if constexpr (N == 6) asm volatile("s_waitcnt vmcnt(6)" ::: "memory");
}

// XCD-chunked bijective block swizzle (requires total % 8 == 0)
__device__ __forceinline__ void xcd_swizzle(int& bx, int& by, int& bz) {
  int gx = gridDim.x, gy = gridDim.y;
  int F = bx + gx * (by + gy * bz);
  int q = (gx * gy * gridDim.z) >> 3;
  int l = (F & 7) * q + (F >> 3);
  bx = l % gx; by = (l / gx) % gy; bz = l / (gx * gy);
}

// ---------------- f32 [C][T] -> f16 [T][C] transpose + fused instance-norm sums ----------------
__global__ __launch_bounds__(256) void transpose_kernel(
    const float* __restrict__ xc, const float* __restrict__ xs,
    f16* __restrict__ xcT, f16* __restrict__ xsT,
    float* __restrict__ sumc, float* __restrict__ sqc,
    float* __restrict__ sums_, float* __restrict__ sqs) {
  const int b = blockIdx.z & 3, which = blockIdx.z >> 2;
  const float* src = (which ? xs : xc) + (long)b * CC * TT;
  f16* dst = (which ? xsT : xcT) + (long)b * TT * CC;
  float* sumP = (which ? sums_ : sumc) + b * CC;
  float* sqP  = (which ? sqs   : sqc ) + b * CC;
  const int t0 = blockIdx.x * 64, c0 = blockIdx.y * 64;
  __shared__ float tile[64][65];
  const int tid = threadIdx.x;
  #pragma unroll
  for (int it = 0; it < 4; ++it) {
    int s = it * 256 + tid, r = s >> 4, q = s & 15;
    float4 v = *(const float4*)&src[(long)(c0 + r) * TT + t0 + q * 4];
    tile[r][q*4+0] = v.x; tile[r][q*4+1] = v.y; tile[r][q*4+2] = v.z; tile[r][q*4+3] = v.w;
    float ps = v.x + v.y + v.z + v.w;
    float pq = v.x*v.x + v.y*v.y + v.z*v.z + v.w*v.w;
    #pragma unroll
    for (int o = 8; o; o >>= 1) { ps += __shfl_xor(ps, o); pq += __shfl_xor(pq, o); }
    if ((tid & 15) == 0) {
      atomicAdd(&sumP[c0 + r], ps);
      atomicAdd(&sqP [c0 + r], pq);
    }
  }
  __syncthreads();
  #pragma unroll
  for (int it = 0; it < 4; ++it) {
    int s = it * 256 + tid, r = s >> 4, q = s & 15;
    f16x4 o;
    o[0] = (f16)tile[q*4+0][r]; o[1] = (f16)tile[q*4+1][r];
    o[2] = (f16)tile[q*4+2][r]; o[3] = (f16)tile[q*4+3][r];
    *(f16x4*)&dst[(long)(t0 + r) * CC + c0 + q * 4] = o;
  }
}

// ---------------- fold instance-norm into conv weights (both Wn and Wm via z) ----------------
__global__ __launch_bounds__(256) void prepw_kernel(
    const float* __restrict__ Wn, const float* __restrict__ bn,
    const float* __restrict__ Wm, const float* __restrict__ bm_,
    const float* __restrict__ sumc, const float* __restrict__ sqc,
    const float* __restrict__ sums_, const float* __restrict__ sqs,
    f16* __restrict__ WnE, float* __restrict__ bnE,
    f16* __restrict__ WmE, float* __restrict__ bmE) {
  const int o = blockIdx.x, b = blockIdx.y, which = blockIdx.z, tid = threadIdx.x;
  const float* W    = which ? Wm : Wn;
  const float* bias = which ? bm_ : bn;
  const float* sum  = which ? sums_ : sumc;
  const float* sq   = which ? sqs : sqc;
  f16* Weff   = which ? WmE : WnE;
  float* beff = which ? bmE : bnE;
  float acc = 0.f;
  #pragma unroll
  for (int j = 0; j < 2; ++j) {
    int c = tid + j * 256;
    float mean = sum[b * CC + c] * (1.f / TT);
    float var  = sq [b * CC + c] * (1.f / TT) - mean * mean;
    float iv = 1.0f / sqrtf(var + 1e-5f);
    float wv = W[(long)o * CC + c] * iv;
    Weff[((long)b * CC + o) * CC + c] = (f16)wv;
    acc += wv * mean;
  }
  #pragma unroll
  for (int off = 32; off; off >>= 1) acc += __shfl_xor(acc, off);
  __shared__ float red[4];
  if ((tid & 63) == 0) red[tid >> 6] = acc;
  __syncthreads();
  if (tid == 0) beff[b * CC + o] = bias[o] - (red[0] + red[1] + red[2] + red[3]);
}

// ---------------- f32 -> f16 convert (Wl and Wo via y) ----------------
__global__ __launch_bounds__(256) void f2h_kernel(const float* __restrict__ s0,
                                                  f16* __restrict__ d0,
                                                  const float* __restrict__ s1,
                                                  f16* __restrict__ d1) {
  const float* src = blockIdx.y ? s1 : s0;
  f16* dst = blockIdx.y ? d1 : d0;
  long i = ((long)blockIdx.x * 256 + threadIdx.x) * 8;
  float4 a = *(const float4*)&src[i], d = *(const float4*)&src[i + 4];
  f16x8 o;
  o[0]=(f16)a.x; o[1]=(f16)a.y; o[2]=(f16)a.z; o[3]=(f16)a.w;
  o[4]=(f16)d.x; o[5]=(f16)d.y; o[6]=(f16)d.z; o[7]=(f16)d.w;
  *(f16x8*)&dst[i] = o;
}

// ---------------- merge per-tile softmax stats -> row m, inv ----------------
__global__ __launch_bounds__(256) void statmerge_kernel(
    const float* __restrict__ gmP, const float* __restrict__ gsP,
    float* __restrict__ m_out, float* __restrict__ inv_out) {
  int idx = blockIdx.x * 256 + threadIdx.x;   // b*TT + t
  int b = idx >> 11, t = idx & (TT - 1);
  float mi[16];
  float M = -3.4e38f;
  #pragma unroll
  for (int i = 0; i < 16; ++i) {
    mi[i] = gmP[((long)i * BB + b) * TT + t];
    M = fmaxf(M, mi[i]);
  }
  float s = 0.f;
  #pragma unroll
  for (int i = 0; i < 16; ++i)
    s += gsP[((long)i * BB + b) * TT + t] * __expf(mi[i] - M);
  m_out[idx] = M;
  inv_out[idx] = 1.0f / s;
}

// ============== triple-buffer depth-2 prefetch GEMM core (counted vmcnt) ==============
// C[M,N] = A[M,K] * BT[N,K]^T. Tile BM x 128, BK=64, NT threads.
// Wave grid: wr = wv>>1 (M), wc = wv&1 (N); wave tile 32x64, acc[2][4].
// LDS XOR-swizzle (row&7)<<4 on staging SOURCE + ds_read (dest linear).
// STATS: emit per-row max & sum-exp partials computed from the f16-ROUNDED
// logits (identical values pv will read back) so softmax errors cancel.
template <int BM, int NT, typename OutT, bool STATS>
__device__ __forceinline__ void gemm_core(
    const f16* __restrict__ A, int lda,
    const f16* __restrict__ BT, int ldb,
    OutT* __restrict__ C, int ldc,
    const float* __restrict__ bias,
    const float* __restrict__ resid, int ldres,
    int bm, int bn, int K, bool transw,
    float* __restrict__ smaxg, float* __restrict__ ssumg) {

  constexpr int CA = BM * 8 / NT;
  constexpr int CB = 128 * 8 / NT;
  constexpr int LOADS = CA + CB;
  constexpr int ABUFB = BM * 128;
  constexpr int BBUFB = 128 * 128;

  __shared__ f16 sA[3 * BM * 64];
  __shared__ f16 sB[3 * 128 * 64];

  const int tid = threadIdx.x, lane = tid & 63, wv = tid >> 6;
  const int wr = wv >> 1, wc = wv & 1;

  const char* gAp[CA]; int lAo[CA];
  #pragma unroll
  for (int i = 0; i < CA; ++i) {
    int cid = tid + i * NT, row = cid >> 3;
    int colb = ((cid & 7) * 16) ^ ((row & 7) << 4);
    gAp[i] = (const char*)A + (long)(bm + row) * lda * 2 + colb;
    lAo[i] = cid * 16;
  }
  const char* gBp[CB]; int lBo[CB];
  #pragma unroll
  for (int i = 0; i < CB; ++i) {
    int cid = tid + i * NT, row = cid >> 3;
    int colb = ((cid & 7) * 16) ^ ((row & 7) << 4);
    gBp[i] = (const char*)BT + (long)(bn + row) * ldb * 2 + colb;
    lBo[i] = cid * 16;
  }

  const int lm = lane & 15, lkb = (lane >> 4) * 16, sw = (lane & 7) << 4;
  int aoff[2][2], boff[4][2];
  #pragma unroll
  for (int mi = 0; mi < 2; ++mi) {
    int r = wr * 32 + mi * 16 + lm;
    #pragma unroll
    for (int kk = 0; kk < 2; ++kk)
      aoff[mi][kk] = r * 128 + ((kk * 64 + lkb) ^ sw);
  }
  #pragma unroll
  for (int ni = 0; ni < 4; ++ni) {
    int r = wc * 64 + ni * 16 + lm;
    #pragma unroll
    for (int kk = 0; kk < 2; ++kk)
      boff[ni][kk] = r * 128 + ((kk * 64 + lkb) ^ sw);
  }

  f32x4 acc[2][4] = {};
  const int nk = K >> 6;

  #pragma unroll
  for (int i = 0; i < CA; ++i) gload16(gAp[i], (char*)sA + lAo[i]);
  #pragma unroll
  for (int i = 0; i < CB; ++i) gload16(gBp[i], (char*)sB + lBo[i]);
  #pragma unroll
  for (int i = 0; i < CA; ++i) gload16(gAp[i] + 128, (char*)sA + ABUFB + lAo[i]);
  #pragma unroll
  for (int i = 0; i < CB; ++i) gload16(gBp[i] + 128, (char*)sB + BBUFB + lBo[i]);

  int s0 = 0;
  for (int kt = 0; kt < nk; ++kt) {
    if (kt + 1 < nk) s_wait_vmcnt<LOADS>(); else s_wait_vmcnt<0>();
    __builtin_amdgcn_s_barrier();

    if (kt + 2 < nk) {
      int s2 = s0 + 2; if (s2 >= 3) s2 -= 3;
      long kb = (long)(kt + 2) * 128;
      int na = s2 * ABUFB, nb = s2 * BBUFB;
      #pragma unroll
      for (int i = 0; i < CA; ++i) gload16(gAp[i] + kb, (char*)sA + na + lAo[i]);
      #pragma unroll
      for (int i = 0; i < CB; ++i) gload16(gBp[i] + kb, (char*)sB + nb + lBo[i]);
    }

    const char* pa = (const char*)sA + s0 * ABUFB;
    const char* pb = (const char*)sB + s0 * BBUFB;
    f16x8 af[2][2], bf[4][2];
    #pragma unroll
    for (int mi = 0; mi < 2; ++mi)
      #pragma unroll
      for (int kk = 0; kk < 2; ++kk)
        af[mi][kk] = *(const f16x8*)(pa + aoff[mi][kk]);
    #pragma unroll
    for (int ni = 0; ni < 4; ++ni)
      #pragma unroll
      for (int kk = 0; kk < 2; ++kk)
        bf[ni][kk] = *(const f16x8*)(pb + boff[ni][kk]);
    #pragma unroll
    for (int kk = 0; kk < 2; ++kk)
      #pragma unroll
      for (int mi = 0; mi < 2; ++mi)
        #pragma unroll
        for (int ni = 0; ni < 4; ++ni)
          acc[mi][ni] = __builtin_amdgcn_mfma_f32_16x16x32_f16(af[mi][kk], bf[ni][kk], acc[mi][ni], 0, 0, 0);

    __builtin_amdgcn_s_barrier();
    s0 = (s0 == 2) ? 0 : s0 + 1;
  }

  // ---- optional softmax stats from f16-ROUNDED logits (consistency with pv) ----
  if constexpr (STATS) {
    __shared__ float s_mx[2][128];
    __shared__ float s_sm[2][128];
    #pragma unroll
    for (int mi = 0; mi < 2; ++mi) {
      #pragma unroll
      for (int r = 0; r < 4; ++r) {
        float sv[4];
        #pragma unroll
        for (int ni = 0; ni < 4; ++ni) sv[ni] = (float)(f16)acc[mi][ni][r];
        float mx = sv[0];
        #pragma unroll
        for (int ni = 1; ni < 4; ++ni) mx = fmaxf(mx, sv[ni]);
        #pragma unroll
        for (int o = 1; o < 16; o <<= 1) mx = fmaxf(mx, __shfl_xor(mx, o));
        float se = 0.f;
        #pragma unroll
        for (int ni = 0; ni < 4; ++ni) se += __expf(sv[ni] - mx);
        #pragma unroll
        for (int o = 1; o < 16; o <<= 1) se += __shfl_xor(se, o);
        if (lm == 0) {
          int row = wr * 32 + mi * 16 + (lane >> 4) * 4 + r;
          s_mx[wc][row] = mx; s_sm[wc][row] = se;
        }
      }
    }
    __syncthreads();
    if (tid < 128) {
      float m0 = s_mx[0][tid], m1 = s_mx[1][tid];
      float M = fmaxf(m0, m1);
      float Ss = s_sm[0][tid] * __expf(m0 - M) + s_sm[1][tid] * __expf(m1 - M);
      smaxg[tid] = M; ssumg[tid] = Ss;
    }
  }

  // ---- epilogue ----
  struct alignas(4 * sizeof(OutT)) Pack4 { OutT v[4]; };
  const int rr = (lane >> 4) * 4;
  #pragma unroll
  for (int mi = 0; mi < 2; ++mi) {
    int m0 = bm + wr * 32 + mi * 16 + rr;
    #pragma unroll
    for (int ni = 0; ni < 4; ++ni) {
      int n0 = bn + wc * 64 + ni * 16 + lm;
      f32x4 v = acc[mi][ni];
      float vals[4];
      #pragma unroll
      for (int r = 0; r < 4; ++r) {
        vals[r] = v[r];
        if (bias)  vals[r] += bias[m0 + r];
        if (resid) vals[r] += resid[(long)(m0 + r) * ldres + n0];
      }
      if (transw) {
        Pack4 pk;
        #pragma unroll
        for (int r = 0; r < 4; ++r) pk.v[r] = (OutT)vals[r];
        *(Pack4*)&C[(long)n0 * ldc + m0] = pk;
      } else {
        #pragma unroll
        for (int r = 0; r < 4; ++r)
          C[(long)(m0 + r) * ldc + n0] = (OutT)vals[r];
      }
    }
  }
}

// ---- merged conv GEMMs: z = cid*4 + b ----
__global__ __launch_bounds__(512) void conv_kernel(
    const f16* __restrict__ xcT, const f16* __restrict__ xsT,
    const f16* __restrict__ WnE, const float* __restrict__ bnE,
    const f16* __restrict__ WmE, const float* __restrict__ bmE,
    const f16* __restrict__ WlB, const float* __restrict__ bl,
    f16* __restrict__ MnT, f16* __restrict__ MmT, f16* __restrict__ Ml) {
  int bx = blockIdx.x, by = blockIdx.y, bz = blockIdx.z;
  xcd_swizzle(bx, by, bz);
  const int cid = bz >> 2, b = bz & 3;
  const f16* A; const float* bias; const f16* B; f16* C; int ldc; bool transw;
  if (cid == 0)      { A = WnE + (long)b*CC*CC; bias = bnE + b*CC; B = xcT + (long)b*TT*CC; C = MnT + (long)b*TT*CC; ldc = CC; transw = true; }
  else if (cid == 1) { A = WmE + (long)b*CC*CC; bias = bmE + b*CC; B = xsT + (long)b*TT*CC; C = MmT + (long)b*TT*CC; ldc = CC; transw = true; }
  else               { A = WlB;                 bias = bl;         B = xsT + (long)b*TT*CC; C = Ml  + (long)b*CC*TT; ldc = TT; transw = false; }
  gemm_core<128, 512, f16, false>(A, CC, B, CC, C, ldc, bias, nullptr, 0,
                                  by * 128, bx * 128, CC, transw, nullptr, nullptr);
}

// ---- sgemm with fused softmax stats ----
__global__ __launch_bounds__(512) void sgemm_kernel(
    const f16* __restrict__ MnT, const f16* __restrict__ MmT, f16* __restrict__ S,
    float* __restrict__ gmP, float* __restrict__ gsP) {
  int bx = blockIdx.x, by = blockIdx.y, bz = blockIdx.z;
  xcd_swizzle(bx, by, bz);
  float* smaxg = gmP + ((long)bx * BB + bz) * TT + by * 128;
  float* ssumg = gsP + ((long)bx * BB + bz) * TT + by * 128;
  gemm_core<128, 512, f16, true>(MnT + (long)bz*TT*CC, CC, MmT + (long)bz*TT*CC, CC,
                                 S + (long)bz*TT*TT, TT, nullptr, nullptr, 0,
                                 by * 128, bx * 128, CC, false, smaxg, ssumg);
}

// ---- pv: MoT[t][c] = sum_s exp(S[t][s]-m[t])*inv[t] * Ml[c][s] ----
// Tile 256(t) x 64(c), K=2048, 512 thr (8 waves, wave tile 32x64).
// A (S) reg-staged with exp transform -> swizzled ds_write; B (Ml) via gload_lds.
__global__ __launch_bounds__(512) void pv_kernel(
    const f16* __restrict__ Sg, const f16* __restrict__ Ml,
    const float* __restrict__ gm, const float* __restrict__ ginv,
    f16* __restrict__ MoT) {
  int bx = blockIdx.x, by = blockIdx.y, bz = blockIdx.z;
  xcd_swizzle(bx, by, bz);
  const f16* A  = Sg + (long)bz * TT * TT;
  const f16* BT = Ml + (long)bz * CC * TT;
  const float* mrow = gm  + bz * TT;
  const float* irow = ginv + bz * TT;
  f16* C = MoT + (long)bz * TT * CC;
  const int bm = by * 256, bn = bx * 64;

  constexpr int ABUFB = 256 * 128;   // 32KB per slot
  constexpr int BBUFB = 64 * 128;    // 8KB per slot
  __shared__ f16 sA[3 * 256 * 64];
  __shared__ f16 sB[3 * 64 * 64];

  const int tid = threadIdx.x, lane = tid & 63, wv = tid >> 6;

  // A reg-stage: 4 chunks/thread (rows 0..255, 8 f16 each)
  const char* gAp[4]; int aw[4]; float am[4];
  #pragma unroll
  for (int i = 0; i < 4; ++i) {
    int cid = tid + i * 512, row = cid >> 3;
    gAp[i] = (const char*)(A + (long)(bm + row) * TT + (cid & 7) * 8);
    aw[i] = row * 128 + (((cid & 7) * 16) ^ ((row & 7) << 4));
    am[i] = mrow[bm + row];
  }
  // B gload chunk (1/thread), pre-swizzled source
  const int brow = tid >> 3;
  const char* gBp = (const char*)BT + (long)(bn + brow) * TT * 2 + (((tid & 7) * 16) ^ ((brow & 7) << 4));
  char* lB = (char*)sB + tid * 16;

  const int lm = lane & 15, lkb = (lane >> 4) * 16, sw = (lane & 7) << 4;
  int aoff[2][2], boff[4][2];
  #pragma unroll
  for (int mi = 0; mi < 2; ++mi) {
    int r = wv * 32 + mi * 16 + lm;
    #pragma unroll
    for (int kk = 0; kk < 2; ++kk)
      aoff[mi][kk] = r * 128 + ((kk * 64 + lkb) ^ sw);
  }
  #pragma unroll
  for (int ni = 0; ni < 4; ++ni) {
    int r = ni * 16 + lm;
    #pragma unroll
    for (int kk = 0; kk < 2; ++kk)
      boff[ni][kk] = r * 128 + ((kk * 64 + lkb) ^ sw);
  }

  f32x4 acc[2][4] = {};
  const int nk = TT >> 6;   // 32

  // ---- prologue ----
  gload16(gBp, lB);                  // B tile0 -> slot0
  gload16(gBp + 128, lB + BBUFB);    // B tile1 -> slot1
  f16x8 ar[4];
  #pragma unroll
  for (int i = 0; i < 4; ++i) ar[i] = *(const f16x8*)gAp[i];      // A tile0
  #pragma unroll
  for (int i = 0; i < 4; ++i) {       // exp-transform tile0 -> slot0
    f16x8 v = ar[i]; f16x8 o;
    #pragma unroll
    for (int j = 0; j < 8; ++j) o[j] = (f16)__expf((float)v[j] - am[i]);
    *(f16x8*)((char*)sA + aw[i]) = o;
  }
  #pragma unroll
  for (int i = 0; i < 4; ++i) ar[i] = *(const f16x8*)(gAp[i] + 128);  // A tile1
  asm volatile("s_waitcnt lgkmcnt(0)" ::: "memory");
  __builtin_amdgcn_s_barrier();

  for (int kt = 0; kt < nk; ++kt) {
    const int s0 = kt % 3;
    if (kt + 2 < nk)
      gload16(gBp + (long)(kt + 2) * 128, lB + ((kt + 2) % 3) * BBUFB);

    const char* pa = (const char*)sA + s0 * ABUFB;
    const char* pb = (const char*)sB + s0 * BBUFB;
    f16x8 af[2][2], bf[4][2];
    #pragma unroll
    for (int mi = 0; mi < 2; ++mi)
      #pragma unroll
      for (int kk = 0; kk < 2; ++kk)
        af[mi][kk] = *(const f16x8*)(pa + aoff[mi][kk]);
    #pragma unroll
    for (int ni = 0; ni < 4; ++ni)
      #pragma unroll
      for (int kk = 0; kk < 2; ++kk)
        bf[ni][kk] = *(const f16x8*)(pb + boff[ni][kk]);
    #pragma unroll
    for (int kk = 0; kk < 2; ++kk)
      #pragma unroll
      for (int mi = 0; mi < 2; ++mi)
        #pragma unroll
        for (int ni = 0; ni < 4; ++ni)
          acc[mi][ni] = __builtin_amdgcn_mfma_f32_16x16x32_f16(af[mi][kk], bf[ni][kk], acc[mi][ni], 0, 0, 0);

    if (kt + 1 < nk) {
      const int s1b = ((kt + 1) % 3) * ABUFB;
      #pragma unroll
      for (int i = 0; i < 4; ++i) {    // exp-transform tile kt+1 (compiler waits its loads)
        f16x8 v = ar[i]; f16x8 o;
        #pragma unroll
        for (int j = 0; j < 8; ++j) o[j] = (f16)__expf((float)v[j] - am[i]);
        *(f16x8*)((char*)sA + s1b + aw[i]) = o;
      }
      if (kt + 2 < nk) {
        #pragma unroll
        for (int i = 0; i < 4; ++i) ar[i] = *(const f16x8*)(gAp[i] + (long)(kt + 2) * 128);
      }
    }
    asm volatile("s_waitcnt lgkmcnt(0)" ::: "memory");
    __builtin_amdgcn_s_barrier();
  }

  // ---- epilogue: scale by inv[t], write MoT[t][c] ----
  const int rr = (lane >> 4) * 4;
  float iv[2][4];
  #pragma unroll
  for (int mi = 0; mi < 2; ++mi)
    #pragma unroll
    for (int r = 0; r < 4; ++r)
      iv[mi][r] = irow[bm + wv * 32 + mi * 16 + rr + r];
  #pragma unroll
  for (int mi = 0; mi < 2; ++mi) {
    int m0 = bm + wv * 32 + mi * 16 + rr;
    #pragma unroll
    for (int ni = 0; ni < 4; ++ni) {
      int n0 = bn + ni * 16 + lm;
      f32x4 v = acc[mi][ni];
      #pragma unroll
      for (int r = 0; r < 4; ++r)
        C[(long)(m0 + r) * CC + n0] = (f16)(v[r] * iv[mi][r]);
    }
  }
}

__global__ __launch_bounds__(256) void out_kernel(
    const f16* __restrict__ WoB, const f16* __restrict__ MoT,
    const float* __restrict__ bo, const float* __restrict__ xc, float* __restrict__ out) {
  int bx = blockIdx.x, by = blockIdx.y, bz = blockIdx.z;
  xcd_swizzle(bx, by, bz);
  gemm_core<64, 256, float, false>(WoB, CC, MoT + (long)bz*TT*CC, CC,
                                   out + (long)bz*CC*TT, TT, bo, xc + (long)bz*CC*TT, TT,
                                   by * 64, bx * 128, CC, false, nullptr, nullptr);
}

extern "C" void kernel_launch(void* const* d_in, const int* in_sizes, int n_in,
                              void* d_out, int out_size, void* d_ws, size_t ws_size,
                              hipStream_t stream) {
  const float* x_c = (const float*)d_in[0];
  const float* x_s = (const float*)d_in[1];
  const float* Wn  = (const float*)d_in[2];
  const float* bn  = (const float*)d_in[3];
  const float* Wm  = (const float*)d_in[4];
  const float* bm  = (const float*)d_in[5];
  const float* Wl  = (const float*)d_in[6];
  const float* bl  = (const float*)d_in[7];
  const float* Wo  = (const float*)d_in[8];
  const float* bo  = (const float*)d_in[9];
  float* out = (float*)d_out;

  char* w = (char*)d_ws;
  auto alloc = [&](size_t bytes) { char* p = w; w += (bytes + 255) & ~(size_t)255; return p; };
  float* sumc  = (float*)alloc(BB * CC * 4);
  float* sqc   = (float*)alloc(BB * CC * 4);
  float* sums_ = (float*)alloc(BB * CC * 4);
  float* sqs   = (float*)alloc(BB * CC * 4);
  float* bnE   = (float*)alloc(BB * CC * 4);
  float* bmE   = (float*)alloc(BB * CC * 4);
  f16* WnE = (f16*)alloc((size_t)BB * CC * CC * 2);
  f16* WmE = (f16*)alloc((size_t)BB * CC * CC * 2);
  f16* WlB = (f16*)alloc((size_t)CC * CC * 2);
  f16* WoB = (f16*)alloc((size_t)CC * CC * 2);
  f16* xcT = (f16*)alloc((size_t)BB * TT * CC * 2);
  f16* xsT = (f16*)alloc((size_t)BB * TT * CC * 2);
  f16* MnT = (f16*)alloc((size_t)BB * TT * CC * 2);
  f16* MmT = (f16*)alloc((size_t)BB * TT * CC * 2);
  f16* Ml  = (f16*)alloc((size_t)BB * CC * TT * 2);
  f16* S   = (f16*)alloc((size_t)BB * TT * TT * 2);
  f16* MoT = (f16*)alloc((size_t)BB * TT * CC * 2);
  float* gmP = (float*)alloc((size_t)16 * BB * TT * 4);
  float* gsP = (float*)alloc((size_t)16 * BB * TT * 4);
  float* gM  = (float*)alloc((size_t)BB * TT * 4);
  float* gInv= (float*)alloc((size_t)BB * TT * 4);

  hipMemsetAsync(sumc, 0, (size_t)4 * BB * CC * 4, stream);

  transpose_kernel<<<dim3(TT / 64, CC / 64, BB * 2), dim3(256), 0, stream>>>(
      x_c, x_s, xcT, xsT, sumc, sqc, sums_, sqs);
  prepw_kernel<<<dim3(CC, BB, 2), dim3(256), 0, stream>>>(
      Wn, bn, Wm, bm, sumc, sqc, sums_, sqs, WnE, bnE, WmE, bmE);
  f2h_kernel<<<dim3(CC * CC / (256 * 8), 2), dim3(256), 0, stream>>>(Wl, WlB, Wo, WoB);

  conv_kernel<<<dim3(16, 4, 12), dim3(512), 0, stream>>>(
      xcT, xsT, WnE, bnE, WmE, bmE, WlB, bl, MnT, MmT, Ml);
  sgemm_kernel<<<dim3(16, 16, BB), dim3(512), 0, stream>>>(MnT, MmT, S, gmP, gsP);
  statmerge_kernel<<<dim3(BB * TT / 256), dim3(256), 0, stream>>>(gmP, gsP, gM, gInv);
  pv_kernel<<<dim3(8, 8, BB), dim3(512), 0, stream>>>(S, Ml, gM, gInv, MoT);
  out_kernel<<<dim3(16, 8, BB), dim3(256), 0, stream>>>(WoB, MoT, bo, x_c, out);
}

// Round 9
// 219.194 us; speedup vs baseline: 1.1404x; 1.1404x over previous
//
#include <hip/hip_runtime.h>
#include <hip/hip_bf16.h>
#include <stdint.h>

typedef _Float16 f16;
typedef _Float16 f16x8 __attribute__((ext_vector_type(8)));
typedef _Float16 f16x4 __attribute__((ext_vector_type(4)));
typedef float    f32x4 __attribute__((ext_vector_type(4)));

#define BB 4
#define CC 512
#define TT 2048

__device__ __forceinline__ void gload16(const void* g, void* l) {
  __builtin_amdgcn_global_load_lds((const __attribute__((address_space(1))) void*)g,
                                   (__attribute__((address_space(3))) void*)l, 16, 0, 0);
}

template <int N>
__device__ __forceinline__ void s_wait_vmcnt() {
  if constexpr (N == 0)      asm volatile("s_waitcnt vmcnt(0)" ::: "memory");
  else if constexpr (N == 4) asm volatile("s_waitcnt vmcnt(4)" ::: "memory");
  else if constexpr (N == 6) asm volatile("s_waitcnt vmcnt(6)" ::: "memory");
}

// XCD-chunked bijective block swizzle (requires total % 8 == 0)
__device__ __forceinline__ void xcd_swizzle(int& bx, int& by, int& bz) {
  int gx = gridDim.x, gy = gridDim.y;
  int F = bx + gx * (by + gy * bz);
  int q = (gx * gy * gridDim.z) >> 3;
  int l = (F & 7) * q + (F >> 3);
  bx = l % gx; by = (l / gx) % gy; bz = l / (gx * gy);
}

// ---------------- f32 [C][T] -> f16 [T][C] transpose + fused instance-norm sums ----------------
__global__ __launch_bounds__(256) void transpose_kernel(
    const float* __restrict__ xc, const float* __restrict__ xs,
    f16* __restrict__ xcT, f16* __restrict__ xsT,
    float* __restrict__ sumc, float* __restrict__ sqc,
    float* __restrict__ sums_, float* __restrict__ sqs) {
  const int b = blockIdx.z & 3, which = blockIdx.z >> 2;
  const float* src = (which ? xs : xc) + (long)b * CC * TT;
  f16* dst = (which ? xsT : xcT) + (long)b * TT * CC;
  float* sumP = (which ? sums_ : sumc) + b * CC;
  float* sqP  = (which ? sqs   : sqc ) + b * CC;
  const int t0 = blockIdx.x * 64, c0 = blockIdx.y * 64;
  __shared__ float tile[64][65];
  const int tid = threadIdx.x;
  #pragma unroll
  for (int it = 0; it < 4; ++it) {
    int s = it * 256 + tid, r = s >> 4, q = s & 15;
    float4 v = *(const float4*)&src[(long)(c0 + r) * TT + t0 + q * 4];
    tile[r][q*4+0] = v.x; tile[r][q*4+1] = v.y; tile[r][q*4+2] = v.z; tile[r][q*4+3] = v.w;
    float ps = v.x + v.y + v.z + v.w;
    float pq = v.x*v.x + v.y*v.y + v.z*v.z + v.w*v.w;
    #pragma unroll
    for (int o = 8; o; o >>= 1) { ps += __shfl_xor(ps, o); pq += __shfl_xor(pq, o); }
    if ((tid & 15) == 0) {
      atomicAdd(&sumP[c0 + r], ps);
      atomicAdd(&sqP [c0 + r], pq);
    }
  }
  __syncthreads();
  #pragma unroll
  for (int it = 0; it < 4; ++it) {
    int s = it * 256 + tid, r = s >> 4, q = s & 15;
    f16x4 o;
    o[0] = (f16)tile[q*4+0][r]; o[1] = (f16)tile[q*4+1][r];
    o[2] = (f16)tile[q*4+2][r]; o[3] = (f16)tile[q*4+3][r];
    *(f16x4*)&dst[(long)(t0 + r) * CC + c0 + q * 4] = o;
  }
}

// ---------------- fold instance-norm into conv weights (both Wn and Wm via z) ----------------
__global__ __launch_bounds__(256) void prepw_kernel(
    const float* __restrict__ Wn, const float* __restrict__ bn,
    const float* __restrict__ Wm, const float* __restrict__ bm_,
    const float* __restrict__ sumc, const float* __restrict__ sqc,
    const float* __restrict__ sums_, const float* __restrict__ sqs,
    f16* __restrict__ WnE, float* __restrict__ bnE,
    f16* __restrict__ WmE, float* __restrict__ bmE) {
  const int o = blockIdx.x, b = blockIdx.y, which = blockIdx.z, tid = threadIdx.x;
  const float* W    = which ? Wm : Wn;
  const float* bias = which ? bm_ : bn;
  const float* sum  = which ? sums_ : sumc;
  const float* sq   = which ? sqs : sqc;
  f16* Weff   = which ? WmE : WnE;
  float* beff = which ? bmE : bnE;
  float acc = 0.f;
  #pragma unroll
  for (int j = 0; j < 2; ++j) {
    int c = tid + j * 256;
    float mean = sum[b * CC + c] * (1.f / TT);
    float var  = sq [b * CC + c] * (1.f / TT) - mean * mean;
    float iv = 1.0f / sqrtf(var + 1e-5f);
    float wv = W[(long)o * CC + c] * iv;
    Weff[((long)b * CC + o) * CC + c] = (f16)wv;
    acc += wv * mean;
  }
  #pragma unroll
  for (int off = 32; off; off >>= 1) acc += __shfl_xor(acc, off);
  __shared__ float red[4];
  if ((tid & 63) == 0) red[tid >> 6] = acc;
  __syncthreads();
  if (tid == 0) beff[b * CC + o] = bias[o] - (red[0] + red[1] + red[2] + red[3]);
}

// ---------------- f32 -> f16 convert (Wl and Wo via y) ----------------
__global__ __launch_bounds__(256) void f2h_kernel(const float* __restrict__ s0,
                                                  f16* __restrict__ d0,
                                                  const float* __restrict__ s1,
                                                  f16* __restrict__ d1) {
  const float* src = blockIdx.y ? s1 : s0;
  f16* dst = blockIdx.y ? d1 : d0;
  long i = ((long)blockIdx.x * 256 + threadIdx.x) * 8;
  float4 a = *(const float4*)&src[i], d = *(const float4*)&src[i + 4];
  f16x8 o;
  o[0]=(f16)a.x; o[1]=(f16)a.y; o[2]=(f16)a.z; o[3]=(f16)a.w;
  o[4]=(f16)d.x; o[5]=(f16)d.y; o[6]=(f16)d.z; o[7]=(f16)d.w;
  *(f16x8*)&dst[i] = o;
}

// ---------------- row softmax over f16 S, in place ----------------
__global__ __launch_bounds__(256) void softmax_kernel(f16* __restrict__ S) {
  f16* p = S + ((long)blockIdx.y * TT + blockIdx.x) * TT;
  const int tid = threadIdx.x;
  f16x8 v8 = ((const f16x8*)p)[tid];
  float v[8];
  #pragma unroll
  for (int j = 0; j < 8; ++j) v[j] = (float)v8[j];
  float m = v[0];
  #pragma unroll
  for (int j = 1; j < 8; ++j) m = fmaxf(m, v[j]);
  #pragma unroll
  for (int o = 32; o; o >>= 1) m = fmaxf(m, __shfl_xor(m, o));
  __shared__ float red[4], red2[4];
  if (!(tid & 63)) red[tid >> 6] = m;
  __syncthreads();
  m = fmaxf(fmaxf(red[0], red[1]), fmaxf(red[2], red[3]));
  float e[8], sum = 0.f;
  #pragma unroll
  for (int j = 0; j < 8; ++j) { e[j] = __expf(v[j] - m); sum += e[j]; }
  #pragma unroll
  for (int o = 32; o; o >>= 1) sum += __shfl_xor(sum, o);
  if (!(tid & 63)) red2[tid >> 6] = sum;
  __syncthreads();
  sum = red2[0] + red2[1] + red2[2] + red2[3];
  float is = 1.f / sum;
  f16x8 o8;
  #pragma unroll
  for (int j = 0; j < 8; ++j) o8[j] = (f16)(e[j] * is);
  ((f16x8*)p)[tid] = o8;
}

// ============== double-buffer prefetched GEMM core with counted vmcnt ==============
// C[M,N] = A[M,K] * BT[N,K]^T. Tile BM x 128, BK=64, NT threads.
// Wave grid: wr = wv>>1 (M), wc = wv&1 (N); wave tile 32x64, acc[2][4].
// LDS XOR-swizzle (row&7)<<4 on staging SOURCE + ds_read (dest linear).
// Per iter: issue tile kt+1 -> wait vmcnt(LOADS) [kt ready, kt+1 in flight]
// -> barrier -> MFMA(kt) -> barrier. 2 buffers = 64KB (BM=128) -> 2 blocks/CU.
template <int BM, int NT, typename OutT>
__device__ __forceinline__ void gemm_core(
    const f16* __restrict__ A, int lda,
    const f16* __restrict__ BT, int ldb,
    OutT* __restrict__ C, int ldc,
    const float* __restrict__ bias,
    const float* __restrict__ resid, int ldres,
    int bm, int bn, int K, bool transw) {

  constexpr int CA = BM * 8 / NT;
  constexpr int CB = 128 * 8 / NT;
  constexpr int LOADS = CA + CB;
  constexpr int ABUFB = BM * 128;
  constexpr int BBUFB = 128 * 128;

  __shared__ f16 sA[2 * BM * 64];
  __shared__ f16 sB[2 * 128 * 64];

  const int tid = threadIdx.x, lane = tid & 63, wv = tid >> 6;
  const int wr = wv >> 1, wc = wv & 1;

  const char* gAp[CA]; int lAo[CA];
  #pragma unroll
  for (int i = 0; i < CA; ++i) {
    int cid = tid + i * NT, row = cid >> 3;
    int colb = ((cid & 7) * 16) ^ ((row & 7) << 4);
    gAp[i] = (const char*)A + (long)(bm + row) * lda * 2 + colb;
    lAo[i] = cid * 16;
  }
  const char* gBp[CB]; int lBo[CB];
  #pragma unroll
  for (int i = 0; i < CB; ++i) {
    int cid = tid + i * NT, row = cid >> 3;
    int colb = ((cid & 7) * 16) ^ ((row & 7) << 4);
    gBp[i] = (const char*)BT + (long)(bn + row) * ldb * 2 + colb;
    lBo[i] = cid * 16;
  }

  const int lm = lane & 15, lkb = (lane >> 4) * 16, sw = (lane & 7) << 4;
  int aoff[2][2], boff[4][2];
  #pragma unroll
  for (int mi = 0; mi < 2; ++mi) {
    int r = wr * 32 + mi * 16 + lm;
    #pragma unroll
    for (int kk = 0; kk < 2; ++kk)
      aoff[mi][kk] = r * 128 + ((kk * 64 + lkb) ^ sw);
  }
  #pragma unroll
  for (int ni = 0; ni < 4; ++ni) {
    int r = wc * 64 + ni * 16 + lm;
    #pragma unroll
    for (int kk = 0; kk < 2; ++kk)
      boff[ni][kk] = r * 128 + ((kk * 64 + lkb) ^ sw);
  }

  f32x4 acc[2][4] = {};
  const int nk = K >> 6;

  // prologue: tile 0 -> buffer 0
  #pragma unroll
  for (int i = 0; i < CA; ++i) gload16(gAp[i], (char*)sA + lAo[i]);
  #pragma unroll
  for (int i = 0; i < CB; ++i) gload16(gBp[i], (char*)sB + lBo[i]);

  for (int kt = 0; kt < nk; ++kt) {
    // issue tile kt+1 into the other buffer (its readers finished last iter)
    if (kt + 1 < nk) {
      long kb = (long)(kt + 1) * 128;
      int na = ((kt + 1) & 1) * ABUFB, nb = ((kt + 1) & 1) * BBUFB;
      #pragma unroll
      for (int i = 0; i < CA; ++i) gload16(gAp[i] + kb, (char*)sA + na + lAo[i]);
      #pragma unroll
      for (int i = 0; i < CB; ++i) gload16(gBp[i] + kb, (char*)sB + nb + lBo[i]);
      s_wait_vmcnt<LOADS>();   // tile kt landed, kt+1 still in flight
    } else {
      s_wait_vmcnt<0>();
    }
    __builtin_amdgcn_s_barrier();

    const char* pa = (const char*)sA + (kt & 1) * ABUFB;
    const char* pb = (const char*)sB + (kt & 1) * BBUFB;
    f16x8 af[2][2], bf[4][2];
    #pragma unroll
    for (int mi = 0; mi < 2; ++mi)
      #pragma unroll
      for (int kk = 0; kk < 2; ++kk)
        af[mi][kk] = *(const f16x8*)(pa + aoff[mi][kk]);
    #pragma unroll
    for (int ni = 0; ni < 4; ++ni)
      #pragma unroll
      for (int kk = 0; kk < 2; ++kk)
        bf[ni][kk] = *(const f16x8*)(pb + boff[ni][kk]);
    #pragma unroll
    for (int kk = 0; kk < 2; ++kk)
      #pragma unroll
      for (int mi = 0; mi < 2; ++mi)
        #pragma unroll
        for (int ni = 0; ni < 4; ++ni)
          acc[mi][ni] = __builtin_amdgcn_mfma_f32_16x16x32_f16(af[mi][kk], bf[ni][kk], acc[mi][ni], 0, 0, 0);

    __builtin_amdgcn_s_barrier();   // readers done before buffer is restaged
  }

  // ---- epilogue ----
  struct alignas(4 * sizeof(OutT)) Pack4 { OutT v[4]; };
  const int rr = (lane >> 4) * 4;
  #pragma unroll
  for (int mi = 0; mi < 2; ++mi) {
    int m0 = bm + wr * 32 + mi * 16 + rr;
    #pragma unroll
    for (int ni = 0; ni < 4; ++ni) {
      int n0 = bn + wc * 64 + ni * 16 + lm;
      f32x4 v = acc[mi][ni];
      float vals[4];
      #pragma unroll
      for (int r = 0; r < 4; ++r) {
        vals[r] = v[r];
        if (bias)  vals[r] += bias[m0 + r];
        if (resid) vals[r] += resid[(long)(m0 + r) * ldres + n0];
      }
      if (transw) {
        Pack4 pk;
        #pragma unroll
        for (int r = 0; r < 4; ++r) pk.v[r] = (OutT)vals[r];
        *(Pack4*)&C[(long)n0 * ldc + m0] = pk;
      } else {
        #pragma unroll
        for (int r = 0; r < 4; ++r)
          C[(long)(m0 + r) * ldc + n0] = (OutT)vals[r];
      }
    }
  }
}

// ---- merged conv GEMMs: z = cid*4 + b ----
__global__ __launch_bounds__(512) void conv_kernel(
    const f16* __restrict__ xcT, const f16* __restrict__ xsT,
    const f16* __restrict__ WnE, const float* __restrict__ bnE,
    const f16* __restrict__ WmE, const float* __restrict__ bmE,
    const f16* __restrict__ WlB, const float* __restrict__ bl,
    f16* __restrict__ MnT, f16* __restrict__ MmT, f16* __restrict__ Ml) {
  int bx = blockIdx.x, by = blockIdx.y, bz = blockIdx.z;
  xcd_swizzle(bx, by, bz);
  const int cid = bz >> 2, b = bz & 3;
  const f16* A; const float* bias; const f16* B; f16* C; int ldc; bool transw;
  if (cid == 0)      { A = WnE + (long)b*CC*CC; bias = bnE + b*CC; B = xcT + (long)b*TT*CC; C = MnT + (long)b*TT*CC; ldc = CC; transw = true; }
  else if (cid == 1) { A = WmE + (long)b*CC*CC; bias = bmE + b*CC; B = xsT + (long)b*TT*CC; C = MmT + (long)b*TT*CC; ldc = CC; transw = true; }
  else               { A = WlB;                 bias = bl;         B = xsT + (long)b*TT*CC; C = Ml  + (long)b*CC*TT; ldc = TT; transw = false; }
  gemm_core<128, 512, f16>(A, CC, B, CC, C, ldc, bias, nullptr, 0,
                           by * 128, bx * 128, CC, transw);
}

__global__ __launch_bounds__(512) void sgemm_kernel(
    const f16* __restrict__ MnT, const f16* __restrict__ MmT, f16* __restrict__ S) {
  int bx = blockIdx.x, by = blockIdx.y, bz = blockIdx.z;
  xcd_swizzle(bx, by, bz);
  gemm_core<128, 512, f16>(MnT + (long)bz*TT*CC, CC, MmT + (long)bz*TT*CC, CC,
                           S + (long)bz*TT*TT, TT, nullptr, nullptr, 0,
                           by * 128, bx * 128, CC, false);
}

__global__ __launch_bounds__(512) void pv_kernel(
    const f16* __restrict__ P, const f16* __restrict__ Ml, f16* __restrict__ MoT) {
  int bx = blockIdx.x, by = blockIdx.y, bz = blockIdx.z;
  xcd_swizzle(bx, by, bz);
  gemm_core<128, 512, f16>(P + (long)bz*TT*TT, TT, Ml + (long)bz*CC*TT, TT,
                           MoT + (long)bz*TT*CC, CC, nullptr, nullptr, 0,
                           by * 128, bx * 128, TT, false);
}

__global__ __launch_bounds__(256) void out_kernel(
    const f16* __restrict__ WoB, const f16* __restrict__ MoT,
    const float* __restrict__ bo, const float* __restrict__ xc, float* __restrict__ out) {
  int bx = blockIdx.x, by = blockIdx.y, bz = blockIdx.z;
  xcd_swizzle(bx, by, bz);
  gemm_core<64, 256, float>(WoB, CC, MoT + (long)bz*TT*CC, CC,
                            out + (long)bz*CC*TT, TT, bo, xc + (long)bz*CC*TT, TT,
                            by * 64, bx * 128, CC, false);
}

extern "C" void kernel_launch(void* const* d_in, const int* in_sizes, int n_in,
                              void* d_out, int out_size, void* d_ws, size_t ws_size,
                              hipStream_t stream) {
  const float* x_c = (const float*)d_in[0];
  const float* x_s = (const float*)d_in[1];
  const float* Wn  = (const float*)d_in[2];
  const float* bn  = (const float*)d_in[3];
  const float* Wm  = (const float*)d_in[4];
  const float* bm  = (const float*)d_in[5];
  const float* Wl  = (const float*)d_in[6];
  const float* bl  = (const float*)d_in[7];
  const float* Wo  = (const float*)d_in[8];
  const float* bo  = (const float*)d_in[9];
  float* out = (float*)d_out;

  char* w = (char*)d_ws;
  auto alloc = [&](size_t bytes) { char* p = w; w += (bytes + 255) & ~(size_t)255; return p; };
  float* sumc  = (float*)alloc(BB * CC * 4);
  float* sqc   = (float*)alloc(BB * CC * 4);
  float* sums_ = (float*)alloc(BB * CC * 4);
  float* sqs   = (float*)alloc(BB * CC * 4);
  float* bnE   = (float*)alloc(BB * CC * 4);
  float* bmE   = (float*)alloc(BB * CC * 4);
  f16* WnE = (f16*)alloc((size_t)BB * CC * CC * 2);
  f16* WmE = (f16*)alloc((size_t)BB * CC * CC * 2);
  f16* WlB = (f16*)alloc((size_t)CC * CC * 2);
  f16* WoB = (f16*)alloc((size_t)CC * CC * 2);
  f16* xcT = (f16*)alloc((size_t)BB * TT * CC * 2);
  f16* xsT = (f16*)alloc((size_t)BB * TT * CC * 2);
  f16* MnT = (f16*)alloc((size_t)BB * TT * CC * 2);
  f16* MmT = (f16*)alloc((size_t)BB * TT * CC * 2);
  f16* Ml  = (f16*)alloc((size_t)BB * CC * TT * 2);
  f16* S   = (f16*)alloc((size_t)BB * TT * TT * 2);
  f16* MoT = (f16*)alloc((size_t)BB * TT * CC * 2);

  hipMemsetAsync(sumc, 0, (size_t)4 * BB * CC * 4, stream);

  transpose_kernel<<<dim3(TT / 64, CC / 64, BB * 2), dim3(256), 0, stream>>>(
      x_c, x_s, xcT, xsT, sumc, sqc, sums_, sqs);
  prepw_kernel<<<dim3(CC, BB, 2), dim3(256), 0, stream>>>(
      Wn, bn, Wm, bm, sumc, sqc, sums_, sqs, WnE, bnE, WmE, bmE);
  f2h_kernel<<<dim3(CC * CC / (256 * 8), 2), dim3(256), 0, stream>>>(Wl, WlB, Wo, WoB);

  conv_kernel<<<dim3(16, 4, 12), dim3(512), 0, stream>>>(
      xcT, xsT, WnE, bnE, WmE, bmE, WlB, bl, MnT, MmT, Ml);
  sgemm_kernel<<<dim3(16, 16, BB), dim3(512), 0, stream>>>(MnT, MmT, S);
  softmax_kernel<<<dim3(TT, BB), dim3(256), 0, stream>>>(S);
  pv_kernel<<<dim3(4, 16, BB), dim3(512), 0, stream>>>(S, Ml, MoT);
  out_kernel<<<dim3(16, 8, BB), dim3(256), 0, stream>>>(WoB, MoT, bo, x_c, out);
}